// Round 4
// baseline (344.888 us; speedup 1.0000x reference)
//
#include <hip/hip_runtime.h>

// LIF scan: mem = 0.25*mem + x[t]; spk = (mem >= 1); mem -= spk.
// x: [T=100, 32, 16384] f32. Parallel over N=524288 neurons, sequential in T.
// Memory-bound: 420 MB kernel traffic, floor ~67us @ 6.4 TB/s (fills prove it).
//
// R4: 1 float/thread -> 2048 blocks = 8192 waves = 32 waves/CU (100% occupancy,
// 2x R3) to match the fill kernels' config. CH=10 register window kept (10
// dword loads in flight/wave; in-flight bytes/CU unchanged ~80 KB).
// R1(8 waves/CU)->R3(16 waves/CU) was only -4us: testing whether occupancy
// clears the residual or we're at the floor (then total is harness-dominated:
// ~260us of 800MiB ws-poison fill + d_out fill + 200MiB d_in restore).

constexpr int T = 100;
constexpr int N = 32 * 16384;      // 524288 neurons, 1 thread each
constexpr int CH = 10;             // loads in flight per thread, T = 10 chunks

__global__ __launch_bounds__(256) void lif_kernel(const float* __restrict__ x,
                                                  float* __restrict__ out) {
    const int i = blockIdx.x * 256 + threadIdx.x;   // neuron index
    const float* xp = x + i;
    float* op = out + i;

    float mem = 0.f;

    for (int c = 0; c < T; c += CH) {              // 10 chunks
        float xs[CH];
#pragma unroll
        for (int k = 0; k < CH; ++k)               // 10 independent dword loads
            xs[k] = xp[(size_t)(c + k) * N];

#pragma unroll
        for (int k = 0; k < CH; ++k) {
            // __fmul_rn/__fadd_rn: match numpy's separate mul+add bit-exactly
            // (no FMA contraction) — hard threshold makes ulp drift cascade.
            mem = __fadd_rn(__fmul_rn(0.25f, mem), xs[k]);
            const float s = (mem >= 1.0f) ? 1.0f : 0.0f;
            mem -= s;
            op[(size_t)(c + k) * N] = s;
        }
    }
}

extern "C" void kernel_launch(void* const* d_in, const int* in_sizes, int n_in,
                              void* d_out, int out_size, void* d_ws, size_t ws_size,
                              hipStream_t stream) {
    const float* x = (const float*)d_in[0];
    float* out = (float*)d_out;
    const int blocks = N / 256;     // 2048 -> 8 blocks/CU, 32 waves/CU
    lif_kernel<<<blocks, 256, 0, stream>>>(x, out);
}

// Round 5
// 328.332 us; speedup vs baseline: 1.0504x; 1.0504x over previous
//
#include <hip/hip_runtime.h>

// LIF scan: mem = 0.25*mem + x[t]; spk = (mem >= 1); mem -= spk.
// x: [T=100, 32, 16384] f32. Parallel over N=524288 neurons, sequential in T.
// Memory-bound: 420 MB kernel traffic, floor ~67us @ 6.4 TB/s (fills prove it).
//
// History: R1 float4/8w/4deep=338 | R3 float2/16w/10deep=334 | R4 float1/32w=345.
// Kernel est. ~105us (~4 TB/s), insensitive to TLP/MLP swings -> parallelism
// is not the limiter. R5: R3 base + NONTEMPORAL loads+stores (nt flag, L2
// no-allocate streaming path) — x is read once, out written once, never
// reused; default allocate-on-both churns L2 against the demand stream.

constexpr int T = 100;
constexpr int N = 32 * 16384;      // 524288 neurons
constexpr int NV2 = N / 2;         // 262144 float2 columns
constexpr int CH = 10;             // loads in flight per thread, T = 10 chunks

typedef float v2f __attribute__((ext_vector_type(2)));  // builtin-compatible float2

__global__ __launch_bounds__(256) void lif_kernel(const v2f* __restrict__ x,
                                                  v2f* __restrict__ out) {
    const int i = blockIdx.x * 256 + threadIdx.x;   // float2 column index
    const v2f* xp = x + i;
    v2f* op = out + i;

    v2f mem = {0.f, 0.f};

    for (int c = 0; c < T; c += CH) {              // 10 chunks
        v2f xs[CH];
#pragma unroll
        for (int k = 0; k < CH; ++k)               // 10 independent nt loads
            xs[k] = __builtin_nontemporal_load(xp + (size_t)(c + k) * NV2);

#pragma unroll
        for (int k = 0; k < CH; ++k) {
            const v2f xt = xs[k];
            v2f s;
            // __fmul_rn/__fadd_rn: match numpy's separate mul+add bit-exactly
            // (no FMA contraction) — hard threshold makes ulp drift cascade.
            mem.x = __fadd_rn(__fmul_rn(0.25f, mem.x), xt.x);
            mem.y = __fadd_rn(__fmul_rn(0.25f, mem.y), xt.y);
            s.x = (mem.x >= 1.0f) ? 1.0f : 0.0f;
            s.y = (mem.y >= 1.0f) ? 1.0f : 0.0f;
            mem.x -= s.x;
            mem.y -= s.y;
            __builtin_nontemporal_store(s, op + (size_t)(c + k) * NV2);
        }
    }
}

extern "C" void kernel_launch(void* const* d_in, const int* in_sizes, int n_in,
                              void* d_out, int out_size, void* d_ws, size_t ws_size,
                              hipStream_t stream) {
    const v2f* x = (const v2f*)d_in[0];
    v2f* out = (v2f*)d_out;
    const int blocks = NV2 / 256;   // 1024 -> 4 blocks/CU, 16 waves/CU
    lif_kernel<<<blocks, 256, 0, stream>>>(x, out);
}